// Round 1
// 447.127 us; speedup vs baseline: 1.0345x; 1.0345x over previous
//
#include <hip/hip_runtime.h>
#include <hip/hip_bf16.h>

#define BB 64
#define CC 32
#define HW2 256   // 16*16
#define VV 4096
#define NELEM (BB*CC*HW2)   // 524288
#define PADW 18
#define PADA 324  // 18*18

// ---------------- workspace layout (float offsets) ----------------
#define OFF_F     0
#define OFF_FHAT  (OFF_F     + NELEM)        // 524288
#define OFF_EMBT  (OFF_FHAT  + NELEM)        // 1048576 (tile-major codebook)
#define OFF_ESQ   (OFF_EMBT  + VV*CC)        // 1179648
#define OFF_PW    (OFF_ESQ   + VV)           // 1183744
#define OFF_PB    (OFF_PW    + 4*CC*CC*9)    // 1220608
#define OFF_REST  (OFF_PB    + 4*CC)         // 1220736 (row-major, max 16384*32)
#define OFF_BESTA (OFF_REST  + 16384*CC)     // 1745024 (16384 u64)
#define OFF_BESTB (OFF_BESTA + 2*16384)      // 1777792
#define OFF_LOSS  (OFF_BESTB + 2*16384)      // 1810560
#define OFF_FLAG  (OFF_LOSS  + 1)            // total 7.24 MB < proven ws

// embT layout: embT[v>>6][c][v&63]  (tile stride 2048 floats, row stride 64)
__device__ __forceinline__ int embt_idx(int v, int c) {
    return (v >> 6) * 2048 + c * 64 + (v & 63);
}

// ---------------- dtype probe: is input 0 f32 (1) or bf16 (0)? ----------------
__global__ void k_probe(const void* __restrict__ fin, int* __restrict__ flag) {
    __shared__ int cnt[256];
    int t = threadIdx.x;
    const __hip_bfloat16* p = (const __hip_bfloat16*)fin;
    int local = 0;
    for (int i = t; i < 8192; i += 256) {
        float v = __bfloat162float(p[i]);
        if (!(fabsf(v) < 1e3f)) local++;
    }
    cnt[t] = local;
    __syncthreads();
    for (int s = 128; s > 0; s >>= 1) {
        if (t < s) cnt[t] += cnt[t + s];
        __syncthreads();
    }
    if (t == 0) *flag = (cnt[0] >= 64) ? 1 : 0;
}

// ---------------- prep: decode -> f32 ws (codebook into tile-major embT) ------
__global__ void k_prep(const void* __restrict__ fin,
                       const void* __restrict__ ein,
                       const void* __restrict__ win,
                       const void* __restrict__ bin_,
                       const int* __restrict__ flag,
                       float* __restrict__ f, float* __restrict__ fhat,
                       float* __restrict__ embT, float* __restrict__ pw,
                       float* __restrict__ pb, float* __restrict__ loss) {
    bool isf32 = (*flag != 0);
    int i = blockIdx.x * 256 + threadIdx.x;
    if (i < NELEM) {
        f[i] = isf32 ? ((const float*)fin)[i]
                     : __bfloat162float(((const __hip_bfloat16*)fin)[i]);
        fhat[i] = 0.f;
    }
    if (i < VV*CC) {
        float ev = isf32 ? ((const float*)ein)[i]
                         : __bfloat162float(((const __hip_bfloat16*)ein)[i]);
        int v = i >> 5, c = i & 31;
        embT[embt_idx(v, c)] = ev;
    }
    if (i < 4*CC*CC*9)
        pw[i] = isf32 ? ((const float*)win)[i]
                      : __bfloat162float(((const __hip_bfloat16*)win)[i]);
    if (i < 4*CC)
        pb[i] = isf32 ? ((const float*)bin_)[i]
                      : __bfloat162float(((const __hip_bfloat16*)bin_)[i]);
    if (i == 0) *loss = 0.f;
}

__global__ void k_esq(const float* __restrict__ embT, float* __restrict__ esq) {
    int v = blockIdx.x * 256 + threadIdx.x;
    if (v >= VV) return;
    const float* p = embT + (v >> 6) * 2048 + (v & 63);
    float s = 0.f;
    #pragma unroll
    for (int c = 0; c < CC; ++c) { float e = p[c * 64]; s = fmaf(e, e, s); }
    esq[v] = s;
}

// ---------------- pool for scale 0 only (pn=1), row-major rest, init bestA ----
__global__ void k_pool0(const float* __restrict__ f, const float* __restrict__ fhat,
                        float* __restrict__ rest, unsigned long long* __restrict__ best) {
    int n = threadIdx.x;     // grid (1, 32)
    int c = blockIdx.y;
    if (n >= BB) return;
    if (c == 0) best[n] = 0xFFFFFFFFFFFFFFFFull;
    const float* fb = f + (n * CC + c) * HW2;
    const float* hb = fhat + (n * CC + c) * HW2;
    float s = 0.f;
    for (int h = 0; h < 16; ++h)
        for (int w = 0; w < 16; ++w)
            s += fb[h * 16 + w] - hb[h * 16 + w];
    rest[n * CC + c] = s * (1.f / 256.f);
}

// ---------------- argmin: LDS-FREE. A (2 queries/lane, 32ch) in VGPRs;
// B (8-code tile) is wave-uniform -> scalar s_load_dwordx8 path; v_fmac with
// SGPR operand. No barriers. Math bit-identical to the proven LDS version:
// same fmaf chain order over k ascending, dist = fmaf(-2,acc,xx+es), strict-<
// ascending scan, packed-u64 atomicMin merge (ties -> numpy-first index).
// Block = 4 independent waves x 128 queries = 512 queries x cpw codes.
__global__ __launch_bounds__(256, 4)
void k_argmin(const float* __restrict__ rest, const float* __restrict__ embT,
              const float* __restrict__ esq, unsigned long long* __restrict__ best,
              int Ntot, int cpw) {
    int tid  = threadIdx.x;
    int w    = tid >> 6, lane = tid & 63;
    int q0   = blockIdx.x * 512 + w * 128 + lane;
    int q1   = q0 + 64;
    int v0   = blockIdx.y * cpw;

    bool act0 = (q0 < Ntot), act1 = (q1 < Ntot);
    if (!act0 && !act1) return;          // idle waves on tiny scales: exit (no barriers)
    int qa = act0 ? q0 : (Ntot - 1);
    int qb = act1 ? q1 : (Ntot - 1);

    // ---- A into registers: 2 queries x 32 channels (64 VGPR) ----
    float a0v[32], a1v[32];
    {
        const float4* ra = (const float4*)(rest + qa * CC);
        const float4* rb = (const float4*)(rest + qb * CC);
        #pragma unroll
        for (int c4 = 0; c4 < 8; ++c4) {
            float4 va = ra[c4], vb4 = rb[c4];
            a0v[c4*4+0] = va.x;  a0v[c4*4+1] = va.y;
            a0v[c4*4+2] = va.z;  a0v[c4*4+3] = va.w;
            a1v[c4*4+0] = vb4.x; a1v[c4*4+1] = vb4.y;
            a1v[c4*4+2] = vb4.z; a1v[c4*4+3] = vb4.w;
        }
    }

    // xx exactly as proven kernel: two 16-ch fmaf partials, then sum
    float p0a = 0.f, p1a = 0.f, p0b = 0.f, p1b = 0.f;
    #pragma unroll
    for (int c = 0; c < 16; ++c)  p0a = fmaf(a0v[c], a0v[c], p0a);
    #pragma unroll
    for (int c = 16; c < 32; ++c) p1a = fmaf(a0v[c], a0v[c], p1a);
    #pragma unroll
    for (int c = 0; c < 16; ++c)  p0b = fmaf(a1v[c], a1v[c], p0b);
    #pragma unroll
    for (int c = 16; c < 32; ++c) p1b = fmaf(a1v[c], a1v[c], p1b);
    float xx0 = p0a + p1a;
    float xx1 = p0b + p1b;

    float bd0 = 3.4e38f, bd1 = 3.4e38f;
    int   bi0 = v0,      bi1 = v0;

    int ntiles = cpw >> 3;               // 8 codes per tile
    for (int t = 0; t < ntiles; ++t) {
        int vb = v0 + t * 8;
        // force-uniform bases -> SGPR pointers -> s_load selection
        int boff = __builtin_amdgcn_readfirstlane((vb >> 6) * 2048 + (vb & 63));
        int eoff = __builtin_amdgcn_readfirstlane(vb);
        const float* bt = embT + boff;
        const float* ep = esq + eoff;

        float acc0[8], acc1[8];
        #pragma unroll
        for (int j = 0; j < 8; ++j) { acc0[j] = 0.f; acc1[j] = 0.f; }

        #pragma unroll
        for (int k = 0; k < CC; ++k) {
            float a0 = a0v[k], a1 = a1v[k];
            #pragma unroll
            for (int j = 0; j < 8; ++j) {
                float bv = bt[k * 64 + j];   // wave-uniform: s_load_dwordx8 per k
                acc0[j] = fmaf(a0, bv, acc0[j]);
                acc1[j] = fmaf(a1, bv, acc1[j]);
            }
        }

        #pragma unroll
        for (int j = 0; j < 8; ++j) {
            float es = ep[j];                // wave-uniform: s_load_dwordx8
            float d0 = fmaf(-2.f, acc0[j], xx0 + es);
            if (d0 < bd0) { bd0 = d0; bi0 = vb + j; }
            float d1 = fmaf(-2.f, acc1[j], xx1 + es);
            if (d1 < bd1) { bd1 = d1; bi1 = vb + j; }
        }
    }

    // pack (monotonic-float << 32 | idx) and merge across code-splits
    unsigned u0 = __float_as_uint(bd0);
    unsigned long long mono0 = (u0 & 0x80000000u)
        ? (unsigned long long)(~u0)
        : (unsigned long long)(u0 | 0x80000000u);
    unsigned long long pk0 = (mono0 << 32) | (unsigned long long)(unsigned)bi0;
    unsigned u1 = __float_as_uint(bd1);
    unsigned long long mono1 = (u1 & 0x80000000u)
        ? (unsigned long long)(~u1)
        : (unsigned long long)(u1 | 0x80000000u);
    unsigned long long pk1 = (mono1 << 32) | (unsigned long long)(unsigned)bi1;

    if (act0) atomicMin(best + q0, pk0);
    if (act1) atomicMin(best + q1, pk1);
}

// ---------------- fused: gather + upsample + conv3x3(phi) + f_hat + loss
//                  + pool(next scale) + best-init(next scale)
// grid (64,8) x 256 threads: block = (batch, 4-out-channel octant).
// Same per-thread body as r9 (proven, no spill); double block-level parallelism.
__global__ __launch_bounds__(256)
void k_fuse(const float* __restrict__ embT,
            const unsigned long long* __restrict__ best,
            const float* __restrict__ pw, const float* __restrict__ pb,
            const float* __restrict__ f, float* __restrict__ fhat,
            float* __restrict__ loss,
            float* __restrict__ rest,
            unsigned long long* __restrict__ best_next,
            int pn, int k, int pn_next) {
    __shared__ float h_pad[CC * PADA];  // [c][18*18], halo = zero padding
    __shared__ float extra[CC * 169];   // hs during upsample, then diff[4][256]
    __shared__ float red[4];
    int b = blockIdx.x, co8 = blockIdx.y, t = threadIdx.x;
    int nn = pn * pn;
    int y = t >> 4, x = t & 15;

    // zero h_pad (covers halo; interior overwritten after a barrier)
    for (int i = t; i < CC * PADA; i += 256) h_pad[i] = 0.f;

    if (pn == 16) {
        __syncthreads();   // zeros visible before interior fill
        int id = (int)(unsigned)(best[b * HW2 + t] & 0xFFFFFFFFull);
        const float* er = embT + (id >> 6) * 2048 + (id & 63);
        int ctr = (y + 1) * PADW + (x + 1);
        #pragma unroll
        for (int c = 0; c < CC; ++c)
            h_pad[c * PADA + ctr] = er[c * 64];
    } else {
        float (*hs)[169] = (float(*)[169])extra;
        for (int cell = t; cell < nn; cell += 256) {
            int id = (int)(unsigned)(best[b * nn + cell] & 0xFFFFFFFFull);
            const float* er = embT + (id >> 6) * 2048 + (id & 63);
            #pragma unroll
            for (int c = 0; c < CC; ++c) hs[c][cell] = er[c * 64];
        }
        __syncthreads();   // zeros + hs visible
        float scale = (float)pn / 16.f;
        float sy = (y + 0.5f) * scale - 0.5f;
        sy = fminf(fmaxf(sy, 0.f), (float)(pn - 1));
        int y0 = (int)sy; int y1 = min(y0 + 1, pn - 1); float wy = sy - (float)y0;
        float sx = (x + 0.5f) * scale - 0.5f;
        sx = fminf(fmaxf(sx, 0.f), (float)(pn - 1));
        int x0 = (int)sx; int x1 = min(x0 + 1, pn - 1); float wx = sx - (float)x0;
        float wy0 = 1.f - wy, wx0 = 1.f - wx;
        int ctr = (y + 1) * PADW + (x + 1);
        #pragma unroll
        for (int c = 0; c < CC; ++c) {
            float v00 = hs[c][y0 * pn + x0], v01 = hs[c][y0 * pn + x1];
            float v10 = hs[c][y1 * pn + x0], v11 = hs[c][y1 * pn + x1];
            float a0 = wy0 * v00 + wy * v10;   // contract H first (jax resize order)
            float a1 = wy0 * v01 + wy * v11;
            h_pad[c * PADA + ctr] = wx0 * a0 + wx * a1;
        }
    }
    __syncthreads();   // h_pad ready; all reads of hs/extra done

    float acc[4];
    #pragma unroll
    for (int o = 0; o < 4; ++o) acc[o] = 0.f;
    const float* hbase = h_pad + y * PADW + x;          // top-left neighbor
    const float* wpk = pw + (k * CC + co8 * 4) * (CC * 9);   // block-uniform
    #pragma unroll
    for (int ci_ = 0; ci_ < CC; ++ci_) {
        float hv[9];
        #pragma unroll
        for (int dy = 0; dy < 3; ++dy)
            #pragma unroll
            for (int dx = 0; dx < 3; ++dx)
                hv[dy * 3 + dx] = hbase[ci_ * PADA + dy * PADW + dx];  // imm offsets
        const float* wp = wpk + ci_ * 9;
        #pragma unroll
        for (int o = 0; o < 4; ++o) {
            const float* w9 = wp + o * (CC * 9);
            #pragma unroll
            for (int q = 0; q < 9; ++q) acc[o] = fmaf(hv[q], w9[q], acc[o]);
        }
    }

    float* diff = extra;   // [4][256], safe: extra unread after the h_pad barrier
    float lsum = 0.f;
    int ctr = (y + 1) * PADW + (x + 1);
    #pragma unroll
    for (int o = 0; o < 4; ++o) {
        int co = co8 * 4 + o;
        float hval = h_pad[co * PADA + ctr];
        float outv = hval * 0.5f + (acc[o] + pb[k * CC + co]) * 0.5f;
        int pos = (b * CC + co) * HW2 + t;
        float fh = fhat[pos] + outv;
        fhat[pos] = fh;
        float dd = f[pos] - fh;        // used for loss AND next-scale pooling
        diff[o * HW2 + t] = dd;
        lsum = fmaf(dd, dd, lsum);
    }
    #pragma unroll
    for (int off = 32; off > 0; off >>= 1) lsum += __shfl_down(lsum, off, 64);
    if ((t & 63) == 0) red[t >> 6] = lsum;
    __syncthreads();   // red + diff visible
    if (t == 0)
        atomicAdd(loss, red[0] + red[1] + red[2] + red[3]);

    if (pn_next > 0) {
        int nn2 = pn_next * pn_next;
        for (int q = t; q < nn2 * 4; q += 256) {
            int cell = q % nn2, o = q / nn2;
            int i = cell / pn_next, j = cell % pn_next;
            int s0 = (i * 16) / pn_next, e0 = ((i + 1) * 16 + pn_next - 1) / pn_next;
            int s1 = (j * 16) / pn_next, e1 = ((j + 1) * 16 + pn_next - 1) / pn_next;
            float inv = 1.f / (float)((e0 - s0) * (e1 - s1));
            float s = 0.f;
            for (int h = s0; h < e0; ++h)
                for (int w = s1; w < e1; ++w)
                    s += diff[o * HW2 + h * 16 + w];
            rest[(b * nn2 + cell) * CC + co8 * 4 + o] = s * inv;   // row-major
        }
        if (co8 == 0)
            for (int q = t; q < nn2; q += 256)
                best_next[b * nn2 + q] = 0xFFFFFFFFFFFFFFFFull;
    }
}

// ---------------- writeout: f32 -> out dtype (matches probed input dtype) -----
__global__ void k_out(const float* __restrict__ fhat, const float* __restrict__ loss,
                      const int* __restrict__ flag, void* __restrict__ out) {
    bool isf32 = (*flag != 0);
    int i = blockIdx.x * 256 + threadIdx.x;
    if (i > NELEM) return;
    float v;
    if (i < NELEM) v = fhat[i];
    else           v = (*loss) * (1.25f / (float)NELEM / 8.f);
    if (isf32) ((float*)out)[i] = v;
    else       ((__hip_bfloat16*)out)[i] = __float2bfloat16(v);
}

extern "C" void kernel_launch(void* const* d_in, const int* in_sizes, int n_in,
                              void* d_out, int out_size, void* d_ws, size_t ws_size,
                              hipStream_t stream) {
    const void* fin  = d_in[0];
    const void* ein  = d_in[1];
    const void* win  = d_in[2];
    const void* bin_ = d_in[3];
    float* ws = (float*)d_ws;
    float* f    = ws + OFF_F;
    float* fhat = ws + OFF_FHAT;
    float* embT = ws + OFF_EMBT;
    float* esq  = ws + OFF_ESQ;
    float* pw   = ws + OFF_PW;
    float* pb   = ws + OFF_PB;
    float* rest = ws + OFF_REST;
    unsigned long long* bestA = (unsigned long long*)(ws + OFF_BESTA);
    unsigned long long* bestB = (unsigned long long*)(ws + OFF_BESTB);
    float* loss = ws + OFF_LOSS;
    int*   flag = (int*)(ws + OFF_FLAG);

    static const int PN[8] = {1, 2, 4, 6, 8, 10, 13, 16};
    static const int KK[8] = {0, 0, 1, 1, 2, 2, 3, 3};
    // code-splits per scale: blocks = ceil(Ntot/512) * SP, target ~1024-1700
    static const int SP[8] = {512, 512, 512, 256, 128, 128, 64, 32};

    k_probe<<<1, 256, 0, stream>>>(fin, flag);
    k_prep<<<(NELEM + 255) / 256, 256, 0, stream>>>(fin, ein, win, bin_, flag,
                                                    f, fhat, embT, pw, pb, loss);
    k_esq<<<(VV + 255) / 256, 256, 0, stream>>>(embT, esq);
    k_pool0<<<dim3(1, CC), 256, 0, stream>>>(f, fhat, rest, bestA);

    for (int si = 0; si < 8; ++si) {
        int pn = PN[si];
        int Ntot = BB * pn * pn;
        int Sp = SP[si];
        int cpw = VV / Sp;
        unsigned long long* bcur = (si & 1) ? bestB : bestA;
        unsigned long long* bnxt = (si & 1) ? bestA : bestB;
        int pn_next = (si < 7) ? PN[si + 1] : 0;
        int gx = (Ntot + 511) / 512;
        k_argmin<<<dim3(gx, Sp), 256, 0, stream>>>(rest, embT, esq, bcur, Ntot, cpw);
        k_fuse<<<dim3(BB, 8), 256, 0, stream>>>(embT, bcur, pw, pb, f, fhat, loss,
                                                rest, bnxt, pn, KK[si], pn_next);
    }
    k_out<<<(NELEM + 1 + 255) / 256, 256, 0, stream>>>(fhat, loss, flag, d_out);
}